// Round 4
// baseline (91.123 us; speedup 1.0000x reference)
//
#include <hip/hip_runtime.h>
#include <hip/hip_bf16.h>

// KPConv collapses to: out[c,:] = sum_m s[c,m] * (x[src(c,m),:] @ W[m])
// with s[c,m] = sum of w over neighbors whose argmin kernel point == m.
// Stage 1: W fp32 [16][64][128] -> bf16 [16][128][64] (transposed) in ws.
// Stage 2: 512 blocks x 256 thr (16 centers each, 2 independent blocks/CU):
//   edge weights -> s (LDS, atomic-free); full A tile (16 x 1024 bf16,
//   scale applied) built ONCE in XOR-swizzled LDS with R0's coalesced
//   fill mapping (thread = (row, quarter) -> 4 dense 256B segs/wave);
//   then a ZERO-barrier MFMA K-loop: A from LDS, B direct from L2-hot Wb.
//   4 barriers total (was 17/33); gather latency paid once, overlapped
//   across the 16 independent per-m loads and across the 2 blocks/CU.

#define P 16
#define IN_F 64
#define OUT_F 128
#define NCC 8192
#define KPE 0.6666667f  // float(1.0/1.5), matches numpy f32 promotion

typedef short short8 __attribute__((ext_vector_type(8)));
typedef float floatx4 __attribute__((ext_vector_type(4)));

__device__ inline unsigned short f2bf(float f) {
    __hip_bfloat16 h = __float2bfloat16(f);
    return __builtin_bit_cast(unsigned short, h);
}

// W [m][i][n] fp32 -> Wb [m][n][i] bf16 (coalesced writes, strided reads; tiny)
__global__ __launch_bounds__(256) void kconv_w(const float* __restrict__ Wf,
                                               unsigned short* __restrict__ Wb) {
    int tg = blockIdx.x * 256 + threadIdx.x;   // 131072 total
    int m = tg >> 13;
    int n = (tg >> 6) & 127;
    int i = tg & 63;
    Wb[tg] = f2bf(Wf[(m * 64 + i) * 128 + n]);
}

__global__ __launch_bounds__(256, 2) void kconv_main(
    const float* __restrict__ x, const float* __restrict__ pos,
    const int* __restrict__ esrc, const int* __restrict__ etgt,
    const float* __restrict__ kpts, const unsigned short* __restrict__ Wb,
    float* __restrict__ out)
{
    __shared__ float kps[48];
    __shared__ float wv[256];
    __shared__ int   nnv[256];
    __shared__ float sT[256];    // [m][c]
    __shared__ int   srcT[256];  // [m][c]
    // A tile: 16 rows x 2048 B; 16B-unit XOR swizzle byte ^= (row&7)<<4
    __shared__ __align__(16) unsigned short A_lds[16 * 1024];  // 32 KB

    const int t  = threadIdx.x;
    const int c0 = blockIdx.x * 16;             // 16 centers/block, grid 512

    if (t < 48) kps[t] = kpts[t];

    // ---- per-edge: argmin kernel point + linear influence weight ----
    // Exact-rounding ops: must bit-match numpy's fp32 sq so argmin agrees.
    const int e   = c0 * P + t;                 // 256 edges per block
    const int src = esrc[e];
    const int tgt = etgt[e];
    float rx = __fsub_rn(pos[tgt * 3 + 0], pos[src * 3 + 0]);
    float ry = __fsub_rn(pos[tgt * 3 + 1], pos[src * 3 + 1]);
    float rz = __fsub_rn(pos[tgt * 3 + 2], pos[src * 3 + 2]);
    __syncthreads();                            // kps ready
    float best = 1e30f; int nn = 0;
#pragma unroll
    for (int k = 0; k < 16; ++k) {
        float dx = __fsub_rn(rx, kps[k * 3 + 0]);
        float dy = __fsub_rn(ry, kps[k * 3 + 1]);
        float dz = __fsub_rn(rz, kps[k * 3 + 2]);
        float sq = __fadd_rn(__fadd_rn(__fmul_rn(dx, dx), __fmul_rn(dy, dy)),
                             __fmul_rn(dz, dz));
        if (sq < best) { best = sq; nn = k; }   // strict < == first-min (np.argmin)
    }
    float w = fmaxf(__fsub_rn(1.0f, __fdiv_rn(__fsqrt_rn(best), KPE)), 0.0f);
    wv[t] = w; nnv[t] = nn;
    srcT[(t & 15) * 16 + (t >> 4)] = src;       // [slot m][center]
    __syncthreads();

    // ---- s[c,m] = sum of w where nn == m (atomic-free), stored [m][c] ----
    {
        const int cl = t >> 4, mm = t & 15;
        float sacc = 0.f;
#pragma unroll
        for (int n2 = 0; n2 < 16; ++n2) {
            const int idx = cl * 16 + n2;
            sacc += (nnv[idx] == mm) ? wv[idx] : 0.f;
        }
        sT[mm * 16 + cl] = sacc;
    }
    __syncthreads();

    // ---- build A tile: A[row][m*64+i] = bf16(s[row,m] * x[src,i]) ----
    // thread -> (row = t>>4, quarter aq = t&15): per m, each wave reads
    // 4 dense 256B row-segments (R0's known-good gather shape). 16
    // independent loads pipeline against the single barrier below.
    const float4* x4 = reinterpret_cast<const float4*>(x);
    {
        const int row = t >> 4, aq = t & 15;
        char* Ab = reinterpret_cast<char*>(A_lds);
        const int rbase = row * 2048;
        const int swz   = (row & 7) << 4;
#pragma unroll
        for (int m = 0; m < 16; ++m) {
            const int   srow = srcT[m * 16 + row];
            const float sv   = sT[m * 16 + row];
            const float4 v   = x4[srow * 16 + aq];
            ushort4 pk;
            pk.x = f2bf(sv * v.x); pk.y = f2bf(sv * v.y);
            pk.z = f2bf(sv * v.z); pk.w = f2bf(sv * v.w);
            *reinterpret_cast<ushort4*>(Ab + rbase + ((m * 128 + aq * 8) ^ swz)) = pk;
        }
    }
    __syncthreads();                            // last barrier in the kernel

    // ---- MFMA K-loop: 16x128 tile, K=1024, zero barriers ----
    const short8* wb8 = reinterpret_cast<const short8*>(Wb);
    const char*   Ab  = reinterpret_cast<const char*>(A_lds);

    const int lane = t & 63;
    const int cgi  = t >> 6;                    // 4 waves = 4 col groups of 32
    const int quad = lane >> 4, l16 = lane & 15;

    const int arow = l16 * 2048;
    const int aswz = (l16 & 7) << 4;
    const int bc0  = cgi * 32 + l16;
    const int bc1  = bc0 + 16;

    floatx4 acc0 = {0.f, 0.f, 0.f, 0.f};
    floatx4 acc1 = {0.f, 0.f, 0.f, 0.f};

#pragma unroll 4
    for (int m = 0; m < 16; ++m) {
        // A frags: row l16, bytes m*128 + ks*64 + quad*16 (^ swz)
        const short8 a0 = *reinterpret_cast<const short8*>(
            Ab + arow + ((m * 128 + quad * 16) ^ aswz));
        const short8 a1 = *reinterpret_cast<const short8*>(
            Ab + arow + ((m * 128 + 64 + quad * 16) ^ aswz));
        // B frags: Wb[m][col][ks*32 + quad*8 ..+7] -- 16B contiguous, L2-hot
        const short8 b00 = wb8[(m * 128 + bc0) * 8 + quad];
        const short8 b01 = wb8[(m * 128 + bc0) * 8 + quad + 4];
        const short8 b10 = wb8[(m * 128 + bc1) * 8 + quad];
        const short8 b11 = wb8[(m * 128 + bc1) * 8 + quad + 4];
        // per-acc accumulation order identical to all passing kernels
        acc0 = __builtin_amdgcn_mfma_f32_16x16x32_bf16(a0, b00, acc0, 0, 0, 0);
        acc1 = __builtin_amdgcn_mfma_f32_16x16x32_bf16(a0, b10, acc1, 0, 0, 0);
        acc0 = __builtin_amdgcn_mfma_f32_16x16x32_bf16(a1, b01, acc0, 0, 0, 0);
        acc1 = __builtin_amdgcn_mfma_f32_16x16x32_bf16(a1, b11, acc1, 0, 0, 0);
    }

    // ---- epilogue: C/D layout col=lane&15, row=quad*4+reg ----
    const int colbase = cgi * 32 + l16;
    const int rowbase = c0 + quad * 4;
#pragma unroll
    for (int v = 0; v < 4; ++v) {
        out[(rowbase + v) * 128 + colbase]      = acc0[v];
        out[(rowbase + v) * 128 + colbase + 16] = acc1[v];
    }
}

extern "C" void kernel_launch(void* const* d_in, const int* in_sizes, int n_in,
                              void* d_out, int out_size, void* d_ws, size_t ws_size,
                              hipStream_t stream) {
    const float* x    = (const float*)d_in[0];
    const float* pos  = (const float*)d_in[1];
    const int*   esrc = (const int*)d_in[2];
    const int*   etgt = (const int*)d_in[3];
    const float* kpts = (const float*)d_in[4];
    const float* Wf   = (const float*)d_in[5];
    float* out = (float*)d_out;
    unsigned short* Wb = (unsigned short*)d_ws;   // 262144 B

    hipLaunchKernelGGL(kconv_w, dim3(512), dim3(256), 0, stream, Wf, Wb);
    hipLaunchKernelGGL(kconv_main, dim3(NCC / 16), dim3(256), 0, stream,
                       x, pos, esrc, etgt, kpts, Wb, out);
}

// Round 5
// 80.000 us; speedup vs baseline: 1.1390x; 1.1390x over previous
//
#include <hip/hip_runtime.h>
#include <hip/hip_bf16.h>

// KPConv collapses to: out[c,:] = sum_m s[c,m] * (x[src(c,m),:] @ W[m])
// with s[c,m] = sum of w over neighbors whose argmin kernel point == m.
// Stage 1: W fp32 [16][64][128] -> bf16 [16][128][64] (transposed) in ws.
// Stage 2: fused per-32-center block: edge weights -> s (LDS, atomic-free),
//          then MFMA bf16 GEMM (M=32 rows/block, N=128, K=1024, BK=64),
//          LDS double-buffered, depth-2 register prefetch.
// vs R3 (80.1us): all block barriers are raw s_barrier + lgkmcnt(0)-only
// (T4: never vmcnt(0) in the loop) so prefetched global loads stay in
// flight across barriers; initial Wb prefetches hoisted above phase 1.

#define P 16
#define IN_F 64
#define OUT_F 128
#define NCC 8192
#define KPE 0.6666667f  // float(1.0/1.5), matches numpy f32 promotion

typedef short short8 __attribute__((ext_vector_type(8)));
typedef float floatx4 __attribute__((ext_vector_type(4)));

__device__ inline unsigned short f2bf(float f) {
    __hip_bfloat16 h = __float2bfloat16(f);
    return __builtin_bit_cast(unsigned short, h);
}

// Barrier that does NOT drain vmcnt: LDS-visibility only (lgkmcnt covers
// ds_read+ds_write). Global loads in flight cross it legally (private VGPR
// destinations; compiler auto-waits vmcnt before each use). sched_barrier
// on both sides pins LDS ops / MFMAs on their side of the barrier (rule #18).
__device__ inline void sync_lds_only() {
    asm volatile("s_waitcnt lgkmcnt(0)" ::: "memory");
    __builtin_amdgcn_sched_barrier(0);
    __builtin_amdgcn_s_barrier();
    __builtin_amdgcn_sched_barrier(0);
}

// W [m][i][n] fp32 -> Wb [m][n][i] bf16 (coalesced writes, strided reads; tiny)
__global__ __launch_bounds__(256) void kconv_w(const float* __restrict__ Wf,
                                               unsigned short* __restrict__ Wb) {
    int tg = blockIdx.x * 256 + threadIdx.x;   // 131072 total
    int m = tg >> 13;
    int n = (tg >> 6) & 127;
    int i = tg & 63;
    Wb[tg] = f2bf(Wf[(m * 64 + i) * 128 + n]);
}

__global__ __launch_bounds__(512) void kconv_main(
    const float* __restrict__ x, const float* __restrict__ pos,
    const int* __restrict__ esrc, const int* __restrict__ etgt,
    const float* __restrict__ kpts, const unsigned short* __restrict__ Wb,
    float* __restrict__ out)
{
    __shared__ float kps[48];
    __shared__ float wv[512];
    __shared__ int   nnv[512];
    __shared__ int   srcv[512];
    __shared__ float s_loc[512];                    // [32 centers][16 m]
    __shared__ __align__(16) unsigned short As[2][32 * 72];   // pad 64->72, dbuf
    __shared__ __align__(16) unsigned short Bs[2][128 * 72];  // pad 64->72, dbuf

    const int t  = threadIdx.x;
    const int c0 = blockIdx.x * 32;

    const uint4* wb4 = reinterpret_cast<const uint4*>(Wb);   // 1024 uint4 per m
    // B prefetch for m=0/1: independent of phase 1, issued at kernel entry;
    // with lgkm-only barriers these stay in flight across the whole phase 1.
    uint4 bA0 = wb4[t];
    uint4 bA1 = wb4[t + 512];
    uint4 bB0 = wb4[1024 + t];
    uint4 bB1 = wb4[1024 + t + 512];

    if (t < 48) kps[t] = kpts[t];

    // ---- per-edge: argmin kernel point + linear influence weight ----
    // Exact-rounding ops: must bit-match numpy's fp32 sq so argmin agrees.
    const int e   = c0 * P + t;                  // 512 edges per block
    const int src = esrc[e];
    const int tgt = etgt[e];
    float rx = __fsub_rn(pos[tgt * 3 + 0], pos[src * 3 + 0]);
    float ry = __fsub_rn(pos[tgt * 3 + 1], pos[src * 3 + 1]);
    float rz = __fsub_rn(pos[tgt * 3 + 2], pos[src * 3 + 2]);
    sync_lds_only();                             // kps ready
    float best = 1e30f; int nn = 0;
#pragma unroll
    for (int k = 0; k < 16; ++k) {
        float dx = __fsub_rn(rx, kps[k * 3 + 0]);
        float dy = __fsub_rn(ry, kps[k * 3 + 1]);
        float dz = __fsub_rn(rz, kps[k * 3 + 2]);
        float sq = __fadd_rn(__fadd_rn(__fmul_rn(dx, dx), __fmul_rn(dy, dy)),
                             __fmul_rn(dz, dz));
        if (sq < best) { best = sq; nn = k; }    // strict < == first-min (np.argmin)
    }
    float w = fmaxf(__fsub_rn(1.0f, __fdiv_rn(__fsqrt_rn(best), KPE)), 0.0f);
    wv[t] = w; nnv[t] = nn; srcv[t] = src;
    sync_lds_only();

    // ---- s[c,m] = sum of w where nn == m (atomic-free) ----
    {
        int cl = t >> 4, mm = t & 15;
        float sacc = 0.f;
#pragma unroll
        for (int n2 = 0; n2 < 16; ++n2) {
            int idx = cl * 16 + n2;
            sacc += (nnv[idx] == mm) ? wv[idx] : 0.f;
        }
        s_loc[t] = sacc;
    }
    sync_lds_only();

    // ---- MFMA GEMM: 32x128 block tile, K loop over 16 kernel points ----
    const float4* x4 = reinterpret_cast<const float4*>(x);
    const int ar = t >> 4, aq = t & 15;          // A-fill: row, quarter(4 floats)
    const int bn = t >> 3, bsg = t & 7;          // B-fill chunk 1
    const int bn2 = (t + 512) >> 3, bsg2 = (t + 512) & 7;    // B-fill chunk 2

    const int wave = t >> 6, lane = t & 63;
    const int quad = lane >> 4, l16 = lane & 15;
    const int rgi = wave & 1, cgi = wave >> 1;   // 2 row groups x 4 col groups
    const int aoff  = (rgi * 16 + l16) * 72;
    const int boff0 = (cgi * 32 + l16) * 72;
    const int boff1 = (cgi * 32 + 16 + l16) * 72;
    const int koff  = quad * 8;

    floatx4 acc0 = {0.f, 0.f, 0.f, 0.f};
    floatx4 acc1 = {0.f, 0.f, 0.f, 0.f};

    auto write_buf = [&](int p, int m, const float4& xv,
                         const uint4& b0, const uint4& b1) {
        const float sv = s_loc[ar * 16 + m];
        ushort4 av;
        av.x = f2bf(sv * xv.x); av.y = f2bf(sv * xv.y);
        av.z = f2bf(sv * xv.z); av.w = f2bf(sv * xv.w);
        *reinterpret_cast<ushort4*>(&As[p][ar * 72 + aq * 4]) = av;
        *reinterpret_cast<uint4*>(&Bs[p][bn  * 72 + bsg  * 8]) = b0;
        *reinterpret_cast<uint4*>(&Bs[p][bn2 * 72 + bsg2 * 8]) = b1;
    };
    auto mfma_buf = [&](int p) {
#pragma unroll
        for (int ks = 0; ks < 2; ++ks) {
            short8 a  = *reinterpret_cast<const short8*>(&As[p][aoff  + ks * 32 + koff]);
            short8 b0 = *reinterpret_cast<const short8*>(&Bs[p][boff0 + ks * 32 + koff]);
            acc0 = __builtin_amdgcn_mfma_f32_16x16x32_bf16(a, b0, acc0, 0, 0, 0);
            short8 b1 = *reinterpret_cast<const short8*>(&Bs[p][boff1 + ks * 32 + koff]);
            acc1 = __builtin_amdgcn_mfma_f32_16x16x32_bf16(a, b1, acc1, 0, 0, 0);
        }
    };

    // depth-2 pipeline: two named register sets (static indexing), dbuf LDS.
    float4 xA  = x4[srcv[ar * 16 + 0] * 16 + aq];
    float4 xB  = x4[srcv[ar * 16 + 1] * 16 + aq];

    write_buf(0, 0, xA, bA0, bA1);               // buf0 <- m=0 (consumes set A)
    sync_lds_only();

#pragma unroll
    for (int m = 0; m < 16; m += 2) {
        // even phase: buf0 holds m; issue L(m+2) into set A; write buf1 <- m+1
        if (m + 2 < 16) {
            xA  = x4[srcv[ar * 16 + m + 2] * 16 + aq];
            bA0 = wb4[(m + 2) * 1024 + t];
            bA1 = wb4[(m + 2) * 1024 + t + 512];
        }
        mfma_buf(0);
        write_buf(1, m + 1, xB, bB0, bB1);       // set B loaded 2 phases ago
        sync_lds_only();

        // odd phase: buf1 holds m+1; issue L(m+3) into set B; write buf0 <- m+2
        if (m + 3 < 16) {
            xB  = x4[srcv[ar * 16 + m + 3] * 16 + aq];
            bB0 = wb4[(m + 3) * 1024 + t];
            bB1 = wb4[(m + 3) * 1024 + t + 512];
        }
        mfma_buf(1);
        if (m + 2 < 16) write_buf(0, m + 2, xA, bA0, bA1);
        sync_lds_only();
    }

    // ---- epilogue: C/D layout col=lane&15, row=quad*4+reg ----
    const int colbase = cgi * 32 + l16;
    const int rowbase = c0 + rgi * 16 + quad * 4;
#pragma unroll
    for (int v = 0; v < 4; ++v) {
        out[(rowbase + v) * 128 + colbase]      = acc0[v];
        out[(rowbase + v) * 128 + colbase + 16] = acc1[v];
    }
}

extern "C" void kernel_launch(void* const* d_in, const int* in_sizes, int n_in,
                              void* d_out, int out_size, void* d_ws, size_t ws_size,
                              hipStream_t stream) {
    const float* x    = (const float*)d_in[0];
    const float* pos  = (const float*)d_in[1];
    const int*   esrc = (const int*)d_in[2];
    const int*   etgt = (const int*)d_in[3];
    const float* kpts = (const float*)d_in[4];
    const float* Wf   = (const float*)d_in[5];
    float* out = (float*)d_out;
    unsigned short* Wb = (unsigned short*)d_ws;   // 262144 B

    hipLaunchKernelGGL(kconv_w, dim3(512), dim3(256), 0, stream, Wf, Wb);
    hipLaunchKernelGGL(kconv_main, dim3(NCC / 32), dim3(512), 0, stream,
                       x, pos, esrc, etgt, kpts, Wb, out);
}